// Round 4
// baseline (566.963 us; speedup 1.0000x reference)
//
#include <hip/hip_runtime.h>

// CT parallel-beam pixel-driven back-projection. Static geometry.
// v/v+360 opposing-view fusion: L[2i] = row_v[i], L[2i+1] = row_{v+360}[735-i]
// (reversed), so one address 2*i0 yields all 4 taps as two float2s
// (ds_read2_b64). Packed-fp32 (v_pk_fma_f32) math on float2 accumulators.
#define BATCH 8
#define NVIEW 720
#define NPAIR 360
#define NDET  736
#define IMGH  512
#define IMGW  512

#define DANG_F  ((float)(6.283185307179586 / 720.0))
#define RATIO_F ((float)(0.006641 / 0.0066))
#define UCENTER ((float)((NDET - 1) * 0.5))

typedef float v2f __attribute__((ext_vector_type(2)));

// Staging: 184 chunks of 8 interleaved dwords (= 2 rows x 736). Thread t<184
// owns chunk t: loads rowA[4t..4t+3] and rowB[732-4t..735-4t] (both float4,
// coalesced; B reversed-coalesced) and writes 32B contiguous to LDS.
__device__ __forceinline__ void load_rows(const float* __restrict__ sino,
                                          int pair, int t,
                                          float4& ra, float4& rb) {
    if (t < 184) {
        const int i = 4 * t;
        ra = *(const float4*)(sino + pair * NDET + i);
        rb = *(const float4*)(sino + (pair + NPAIR) * NDET + (732 - i));
    }
}

__device__ __forceinline__ void write_rows(float* __restrict__ L, int t,
                                           float4 ra, float4 rb) {
    if (t < 184) {
        const int i = 4 * t;
        // L[2i+k*2] = A[i+k]; L[2i+k*2+1] = B[735-i-k]
        *(float4*)(L + 2 * i)     = make_float4(ra.x, rb.w, ra.y, rb.z);
        *(float4*)(L + 2 * i + 4) = make_float4(ra.z, rb.y, ra.w, rb.x);
    }
}

// Block = 256: lanes 0..63 = consecutive w, 4 waves = 4 h rows, 4 px/thread
// strided 64 in w. Grid 2048 = 8 blocks/CU. Bounds check proven unnecessary:
// |px*cx+py*cy|*r <= 363.6 < 367.5 -> u in [3.9, 731.1], i0+1 <= 732 < 736.
__global__ __launch_bounds__(256, 8) void backproject_kernel(
    const float* __restrict__ proj,  // [B, V, D]
    float* __restrict__ out)         // [B, H, W]
{
    __shared__ alignas(16) float lds[2][2 * NDET];  // 2 x 1472 floats
    __shared__ v2f cs[NPAIR];

    const int tid = threadIdx.x;

    for (int v = tid; v < NPAIR; v += 256) {
        float s, c;
        sincosf((float)v * DANG_F, &s, &c);
        cs[v] = (v2f){c * RATIO_F, s * RATIO_F};
    }

    const int b    = blockIdx.z;
    const int lane = tid & 63;
    const int h    = (int)blockIdx.y * 4 + (tid >> 6);
    const int w0   = (int)blockIdx.x * 256 + lane;

    const float px0 = (float)w0 - (float)(IMGW - 1) * 0.5f;
    const float py  = (float)(IMGH - 1) * 0.5f - (float)h;
    const v2f px01 = {px0, px0 + 64.0f};
    const v2f px23 = {px0 + 128.0f, px0 + 192.0f};

    const float* __restrict__ sino = proj + (size_t)b * NVIEW * NDET;

    v2f acc0 = {0.f, 0.f}, acc1 = {0.f, 0.f}, acc2 = {0.f, 0.f}, acc3 = {0.f, 0.f};

    float4 ra = {0, 0, 0, 0}, rb = {0, 0, 0, 0};
    load_rows(sino, 0, tid, ra, rb);
    write_rows(lds[0], tid, ra, rb);
    load_rows(sino, 1, tid, ra, rb);
    __syncthreads();

#pragma unroll 2
    for (int pair = 0; pair < NPAIR; ++pair) {
        const int buf = pair & 1;
        const v2f t = cs[pair];
        const float base = fmaf(py, t.y, UCENTER);
        const v2f bb = {base, base};
        const v2f cc = {t.x, t.x};
        const v2f u01 = __builtin_elementwise_fma(px01, cc, bb);
        const v2f u23 = __builtin_elementwise_fma(px23, cc, bb);

        const int i0 = (int)u01.x, i1 = (int)u01.y;
        const int i2 = (int)u23.x, i3 = (int)u23.y;
        const float f0 = __builtin_amdgcn_fractf(u01.x);
        const float f1 = __builtin_amdgcn_fractf(u01.y);
        const float f2 = __builtin_amdgcn_fractf(u23.x);
        const float f3 = __builtin_amdgcn_fractf(u23.y);

        const float* __restrict__ L = lds[buf];
        const v2f V00 = *(const v2f*)(L + 2 * i0);      // (a0, b0) px0
        const v2f V01 = *(const v2f*)(L + 2 * i0 + 2);  // (a1, b1) px0
        const v2f V10 = *(const v2f*)(L + 2 * i1);
        const v2f V11 = *(const v2f*)(L + 2 * i1 + 2);
        const v2f V20 = *(const v2f*)(L + 2 * i2);
        const v2f V21 = *(const v2f*)(L + 2 * i2 + 2);
        const v2f V30 = *(const v2f*)(L + 2 * i3);
        const v2f V31 = *(const v2f*)(L + 2 * i3 + 2);

        acc0 += V00; acc0 = __builtin_elementwise_fma((v2f){f0, f0}, V01 - V00, acc0);
        acc1 += V10; acc1 = __builtin_elementwise_fma((v2f){f1, f1}, V11 - V10, acc1);
        acc2 += V20; acc2 = __builtin_elementwise_fma((v2f){f2, f2}, V21 - V20, acc2);
        acc3 += V30; acc3 = __builtin_elementwise_fma((v2f){f3, f3}, V31 - V30, acc3);

        if (pair < NPAIR - 1) {
            // lds[buf^1] was last read at iter pair-1, sealed by that
            // iteration's barrier -> safe to overwrite now.
            write_rows(lds[buf ^ 1], tid, ra, rb);
            if (pair < NPAIR - 2) load_rows(sino, pair + 2, tid, ra, rb);
            __syncthreads();
        }
    }

    float* __restrict__ o = out + ((size_t)b * IMGH + h) * IMGW + w0;
    o[0]   = (acc0.x + acc0.y) * DANG_F;
    o[64]  = (acc1.x + acc1.y) * DANG_F;
    o[128] = (acc2.x + acc2.y) * DANG_F;
    o[192] = (acc3.x + acc3.y) * DANG_F;
}

extern "C" void kernel_launch(void* const* d_in, const int* in_sizes, int n_in,
                              void* d_out, int out_size, void* d_ws, size_t ws_size,
                              hipStream_t stream) {
    const float* proj = (const float*)d_in[0];
    float* out = (float*)d_out;

    dim3 block(256, 1, 1);
    dim3 grid(IMGW / 256, IMGH / 4, BATCH);  // 2048 blocks = 8/CU
    backproject_kernel<<<grid, block, 0, stream>>>(proj, out);
}

// Round 6
// 333.820 us; speedup vs baseline: 1.6984x; 1.6984x over previous
//
#include <hip/hip_runtime.h>

// CT parallel-beam pixel-driven back-projection. Static geometry.
// Opposing-view fusion (v, v+360): u' = 735 - u. LDS stores fp16 interleaved
// L[i] = (rowA[i], rowB[735-i]) as half2 -> one ds_read2_b32 per pixel gets
// all 4 taps, stride-1-bank (conflict-free). Interp + A/B sum collapses to
// two v_dot2_f32_f16 into a scalar f32 accumulator.
#define BATCH 8
#define NVIEW 720
#define NPAIR 360
#define NDET  736
#define IMGH  512
#define IMGW  512

#define DANG_F  ((float)(6.283185307179586 / 720.0))
#define RATIO_F ((float)(0.006641 / 0.0066))
#define UCENTER ((float)((NDET - 1) * 0.5))

typedef float  v2f __attribute__((ext_vector_type(2)));
typedef __fp16 v2h __attribute__((ext_vector_type(2)));  // matches builtin V2h

// Staging: thread t<184 owns bins 4t..4t+3. Loads rowA[4t..4t+3] and
// rowB[732-4t..735-4t] (float4, coalesced / reverse-coalesced), packs to
// half2 pairs (A[i], B[735-i]) via cvt_pkrtz, one ds_write_b128.
__device__ __forceinline__ void load_rows(const float* __restrict__ sino,
                                          int pair, int t,
                                          float4& ra, float4& rb) {
    if (t < 184) {
        const int i = 4 * t;
        ra = *(const float4*)(sino + pair * NDET + i);
        rb = *(const float4*)(sino + (pair + NPAIR) * NDET + (732 - i));
    }
}

__device__ __forceinline__ void write_rows(v2h* __restrict__ L, int t,
                                           float4 ra, float4 rb) {
    if (t < 184) {
        v2h h0 = __builtin_amdgcn_cvt_pkrtz(ra.x, rb.w);  // bin 4t
        v2h h1 = __builtin_amdgcn_cvt_pkrtz(ra.y, rb.z);  // bin 4t+1
        v2h h2 = __builtin_amdgcn_cvt_pkrtz(ra.z, rb.y);  // bin 4t+2
        v2h h3 = __builtin_amdgcn_cvt_pkrtz(ra.w, rb.x);  // bin 4t+3
        struct alignas(16) H4 { v2h a, b, c, d; };
        *(H4*)(L + 4 * t) = H4{h0, h1, h2, h3};           // ds_write_b128
    }
}

// Block = 256: lanes 0..63 = consecutive w, 4 waves = 4 h rows, 4 px/thread
// strided 64 in w. Grid 2048 = 8 blocks/CU. Bounds check proven unnecessary:
// |px*cx+py*cy|*r <= 363.6 < 367.5 -> u in [3.9, 731.1], i0+1 <= 732 < 736.
__global__ __launch_bounds__(256, 8) void backproject_kernel(
    const float* __restrict__ proj,  // [B, V, D]
    float* __restrict__ out)         // [B, H, W]
{
    __shared__ alignas(16) v2h lds[2][NDET];  // (A[i], Brev[i]) fp16 pairs
    __shared__ v2f cs[NPAIR];

    const int tid = threadIdx.x;

    for (int v = tid; v < NPAIR; v += 256) {
        float s, c;
        sincosf((float)v * DANG_F, &s, &c);
        cs[v] = (v2f){c * RATIO_F, s * RATIO_F};
    }

    const int b    = blockIdx.z;
    const int lane = tid & 63;
    const int h    = (int)blockIdx.y * 4 + (tid >> 6);
    const int w0   = (int)blockIdx.x * 256 + lane;

    const float px0 = (float)w0 - (float)(IMGW - 1) * 0.5f;
    const float py  = (float)(IMGH - 1) * 0.5f - (float)h;
    const v2f px01 = {px0, px0 + 64.0f};
    const v2f px23 = {px0 + 128.0f, px0 + 192.0f};

    const float* __restrict__ sino = proj + (size_t)b * NVIEW * NDET;

    float acc0 = 0.f, acc1 = 0.f, acc2 = 0.f, acc3 = 0.f;

    float4 ra = {0, 0, 0, 0}, rb = {0, 0, 0, 0};
    load_rows(sino, 0, tid, ra, rb);
    write_rows(lds[0], tid, ra, rb);
    load_rows(sino, 1, tid, ra, rb);
    __syncthreads();

#pragma unroll 2
    for (int pair = 0; pair < NPAIR; ++pair) {
        const int buf = pair & 1;
        const v2f t = cs[pair];
        const float base = fmaf(py, t.y, UCENTER);
        const v2f bb = {base, base};
        const v2f cc = {t.x, t.x};
        const v2f u01 = __builtin_elementwise_fma(px01, cc, bb);
        const v2f u23 = __builtin_elementwise_fma(px23, cc, bb);

        const v2h* __restrict__ L = lds[buf];

#pragma unroll
        for (int p = 0; p < 4; ++p) {
            const float u  = (p == 0) ? u01.x : (p == 1) ? u01.y
                           : (p == 2) ? u23.x : u23.y;
            const int   i0 = (int)u;
            const float fr = __builtin_amdgcn_fractf(u);
            const v2h w1 = __builtin_amdgcn_cvt_pkrtz(fr, fr);
            const v2h w0 = __builtin_amdgcn_cvt_pkrtz(1.0f - fr, 1.0f - fr);
            const v2h P  = L[i0];        // (a0, b0)  } one ds_read2_b32
            const v2h Q  = L[i0 + 1];    // (a1, b1)  }
            float* acc = (p == 0) ? &acc0 : (p == 1) ? &acc1
                       : (p == 2) ? &acc2 : &acc3;
            float a = __builtin_amdgcn_fdot2(P, w0, *acc, false);
            *acc    = __builtin_amdgcn_fdot2(Q, w1, a, false);
        }

        if (pair < NPAIR - 1) {
            // lds[buf^1] last read at iter pair-1, sealed by that iteration's
            // barrier -> safe to overwrite now.
            write_rows(lds[buf ^ 1], tid, ra, rb);
            if (pair < NPAIR - 2) load_rows(sino, pair + 2, tid, ra, rb);
            __syncthreads();
        }
    }

    float* __restrict__ o = out + ((size_t)b * IMGH + h) * IMGW + w0;
    o[0]   = acc0 * DANG_F;
    o[64]  = acc1 * DANG_F;
    o[128] = acc2 * DANG_F;
    o[192] = acc3 * DANG_F;
}

extern "C" void kernel_launch(void* const* d_in, const int* in_sizes, int n_in,
                              void* d_out, int out_size, void* d_ws, size_t ws_size,
                              hipStream_t stream) {
    const float* proj = (const float*)d_in[0];
    float* out = (float*)d_out;

    dim3 block(256, 1, 1);
    dim3 grid(IMGW / 256, IMGH / 4, BATCH);  // 2048 blocks = 8/CU
    backproject_kernel<<<grid, block, 0, stream>>>(proj, out);
}

// Round 8
// 280.161 us; speedup vs baseline: 2.0237x; 1.1915x over previous
//
#include <hip/hip_runtime.h>

// CT parallel-beam pixel-driven back-projection. Static geometry.
// Symmetry fusions:
//  1) Opposing views (v, v+360): u' = 735-u -> LDS pair stored fp16
//     interleaved L[i] = (row_v[i], row_{v+360}[735-i]); one ds_read2_b32
//     per visit yields 4 taps; interp = two v_dot2_f32_f16.
//  2) View quad {v, v+180, v+360, v+540} x pixel ROTATION orbit. v+180 is
//     angle+90deg: t_{v+180}(q) = t_v(sigma(q)), sigma(px,py) = (py,-px).
//     With g1 = px*c + py*s, g2 = py*c - px*s, the 16 contributions are the
//     4 visits u = C+-g1, C+-g2: each serves pairA (v,v+360) for pixel q and
//     pairB (v+180,v+540) for pixel sigma^-1(q).
#define BATCH 8
#define NVIEW 720
#define NPAIR 360
#define NGRP  180
#define NDET  736
#define IMGH  512
#define IMGW  512

#define DANG_F  ((float)(6.283185307179586 / 720.0))
#define RATIO_F ((float)(0.006641 / 0.0066))
#define UCENTER ((float)((NDET - 1) * 0.5))

typedef float  v2f __attribute__((ext_vector_type(2)));
typedef __fp16 v2h __attribute__((ext_vector_type(2)));

// Staging: threads 0..183 stage fused pairA (views g, g+360), threads
// 184..367 stage fused pairB (views g+180, g+540). Each owns 4 bins:
// forward row float4 + reversed row float4 (coalesced), packed to
// interleaved half2, one ds_write_b128.
__device__ __forceinline__ void load_rows(const float* __restrict__ sino,
                                          int g, int t,
                                          float4& ra, float4& rb) {
    if (t < 368) {
        const int grp = (t >= 184);
        const int i   = 4 * (t - 184 * grp);
        const int vf  = g + 180 * grp;
        ra = *(const float4*)(sino + vf * NDET + i);
        rb = *(const float4*)(sino + (vf + NPAIR) * NDET + (732 - i));
    }
}

__device__ __forceinline__ void write_rows(v2h* __restrict__ L,  // [2*NDET]
                                           int t, float4 ra, float4 rb) {
    if (t < 368) {
        const int grp = (t >= 184);
        const int i   = 4 * (t - 184 * grp);
        v2h h0 = __builtin_amdgcn_cvt_pkrtz(ra.x, rb.w);
        v2h h1 = __builtin_amdgcn_cvt_pkrtz(ra.y, rb.z);
        v2h h2 = __builtin_amdgcn_cvt_pkrtz(ra.z, rb.y);
        v2h h3 = __builtin_amdgcn_cvt_pkrtz(ra.w, rb.x);
        struct alignas(16) H4 { v2h a, b, c, d; };
        *(H4*)(L + grp * NDET + i) = H4{h0, h1, h2, h3};   // ds_write_b128
    }
}

// One u value: fused 2-view interp from pairA into accA and pairB into accB.
__device__ __forceinline__ void visit(const v2h* __restrict__ L,
                                      float u, float& accA, float& accB) {
    const int   i0 = (int)u;                      // u in [3.9, 731.1] always
    const float fr = __builtin_amdgcn_fractf(u);
    const v2h w1 = __builtin_amdgcn_cvt_pkrtz(fr, fr);
    const v2h w0 = __builtin_amdgcn_cvt_pkrtz(1.0f - fr, 1.0f - fr);
    const v2h PA = L[i0];
    const v2h QA = L[i0 + 1];
    const v2h PB = L[NDET + i0];
    const v2h QB = L[NDET + i0 + 1];
    accA = __builtin_amdgcn_fdot2(QA, w1,
             __builtin_amdgcn_fdot2(PA, w0, accA, false), false);
    accB = __builtin_amdgcn_fdot2(QB, w1,
             __builtin_amdgcn_fdot2(PB, w0, accB, false), false);
}

// 512 threads = 8 waves; wave = one h row of the top-left quadrant, lanes =
// 64 consecutive w. Each thread owns the 4-pixel rotation orbit
// {(h,w), (511-w,h), (511-h,511-w), (w,511-h)} (one per image quadrant).
// Grid 1024 = exactly 4 blocks/CU; launch_bounds(512,8) -> VGPR<=64 -> full
// 32-wave residency. Bounds check proven unnecessary: |g1|,|g2| <=
// 255.5*sqrt2*1.00621 = 363.6 < 367.5 -> u in [3.9, 731.1], i0+1 <= 732.
__global__ __launch_bounds__(512, 8) void backproject_kernel(
    const float* __restrict__ proj,  // [B, V, D]
    float* __restrict__ out)         // [B, H, W]
{
    __shared__ alignas(16) v2h lds[2][2 * NDET];  // [dbuf][pairA | pairB]
    __shared__ v2f cs[NGRP];

    const int tid = threadIdx.x;

    if (tid < NGRP) {
        float s, c;
        sincosf((float)tid * DANG_F, &s, &c);
        cs[tid] = (v2f){c * RATIO_F, s * RATIO_F};
    }

    const int b    = blockIdx.z;
    const int lane = tid & 63;
    const int h    = (int)blockIdx.y * 8 + (tid >> 6);   // [0, 256)
    const int w0   = (int)blockIdx.x * 64 + lane;        // [0, 256)

    const float px = (float)w0 - (float)(IMGW - 1) * 0.5f;
    const float py = (float)(IMGH - 1) * 0.5f - (float)h;

    const float* __restrict__ sino = proj + (size_t)b * NVIEW * NDET;

    // Orbit accumulators: q0=(h,w0), q1=(511-w0,h), q2=(511-h,511-w0),
    // q3=(w0,511-h)   (q_{k+1} = rotate q_k by +90deg in (px,py)).
    float acc0 = 0.f, acc1 = 0.f, acc2 = 0.f, acc3 = 0.f;

    float4 ra = {0, 0, 0, 0}, rb = {0, 0, 0, 0};
    load_rows(sino, 0, tid, ra, rb);
    write_rows(lds[0], tid, ra, rb);
    load_rows(sino, 1, tid, ra, rb);
    __syncthreads();

#pragma unroll 2
    for (int g = 0; g < NGRP; ++g) {
        const int buf = g & 1;
        const v2h* __restrict__ L = lds[buf];
        const v2f t = cs[g];
        // (g1, g2) = px*(c, -s) + py*(s, c)  -- two packed fp32 ops
        const v2f m1 = {t.x, -t.y};
        const v2f m2 = {t.y, t.x};
        const v2f pxv = {px, px};
        const v2f pyv = {py, py};
        const v2f gg = __builtin_elementwise_fma(
            pxv, m1, pyv * m2);
        const v2f cc = {UCENTER, UCENTER};
        const v2f up = cc + gg;   // (C+g1, C+g2)
        const v2f um = cc - gg;   // (C-g1, C-g2)

        // visit(u): pairA -> pixel q with t_v(q)=u-C; pairB -> next orbit
        // pixel (since t_{v+180}(q_{k+1}) = t_v(q_k)).
        visit(L, up.x, acc0, acc1);   // +g1: A->q0, B->q1
        visit(L, um.x, acc2, acc3);   // -g1: A->q2, B->q3
        visit(L, up.y, acc3, acc0);   // +g2: A->q3, B->q0
        visit(L, um.y, acc1, acc2);   // -g2: A->q1, B->q2

        if (g < NGRP - 1) {
            // lds[buf^1] last read at iter g-1, sealed by that iteration's
            // barrier -> safe to overwrite now.
            write_rows(lds[buf ^ 1], tid, ra, rb);
            if (g < NGRP - 2) load_rows(sino, g + 2, tid, ra, rb);
            __syncthreads();
        }
    }

    float* __restrict__ o = out + (size_t)b * IMGH * IMGW;
    const int hm = (IMGH - 1) - h;
    const int wm = (IMGW - 1) - w0;
    o[h  * IMGW + w0] = acc0 * DANG_F;   // q0, coalesced
    o[wm * IMGW + h ] = acc1 * DANG_F;   // q1, scattered (once)
    o[hm * IMGW + wm] = acc2 * DANG_F;   // q2, coalesced
    o[w0 * IMGW + hm] = acc3 * DANG_F;   // q3, scattered (once)
}

extern "C" void kernel_launch(void* const* d_in, const int* in_sizes, int n_in,
                              void* d_out, int out_size, void* d_ws, size_t ws_size,
                              hipStream_t stream) {
    const float* proj = (const float*)d_in[0];
    float* out = (float*)d_out;

    dim3 block(512, 1, 1);
    dim3 grid(4, 32, BATCH);   // 1024 blocks = exactly 4/CU, fully resident
    backproject_kernel<<<grid, block, 0, stream>>>(proj, out);
}

// Round 9
// 245.686 us; speedup vs baseline: 2.3077x; 1.1403x over previous
//
#include <hip/hip_runtime.h>

// CT parallel-beam pixel-driven back-projection. Static geometry.
// Fusions:
//  1) Opposing views (v, v+360) share fr (u' = 735-u): PRE-SUM at staging,
//     S[i] = row_v[i] + row_{v+360}[735-i] (fp32 add, one fp16 round).
//     LDS stores staggered duplicates N[i] = (S[i], S[i+1]) as half2 ->
//     one aligned ds_read_b32 + one pkrtz(1-fr, fr) + one v_dot2_f32_f16
//     does the whole 2-view 2-tap interp.
//  2) View quad {v, v+180, v+360, v+540} x pixel ROTATION orbit (v+180 is
//     +90deg): with g1 = px*c + py*s, g2 = py*c - px*s the 16 contributions
//     are 4 visits u = C+-g1, C+-g2; each serves pairA (v,v+360) for pixel q
//     and pairB (v+180,v+540) for the next orbit pixel. PairB array sits at
//     +2944 B: same address register, immediate DS offset.
#define BATCH 8
#define NVIEW 720
#define NPAIR 360
#define NGRP  180
#define NDET  736
#define IMGH  512
#define IMGW  512

#define DANG_F  ((float)(6.283185307179586 / 720.0))
#define RATIO_F ((float)(0.006641 / 0.0066))
#define UCENTER ((float)((NDET - 1) * 0.5))

typedef float  v2f __attribute__((ext_vector_type(2)));
typedef __fp16 v2h __attribute__((ext_vector_type(2)));

// Staging: threads 0..183 build pairA sums (views g, g+360), threads
// 184..367 pairB (g+180, g+540). Thread owns bins i..i+3 (i = 4*(t%184)):
// needs S[i..i+4] -> float4 + 1 scalar from each of fwd/rev rows.
// Overshoot scalars (fwd[736] at i=732; rev[-1]) stay inside `proj` (fwd
// rows <= 539, rev rows >= 360) and land only in N[735], which is never
// read (i0 <= 731).
__device__ __forceinline__ void load_rows(const float* __restrict__ sino,
                                          int g, int t,
                                          float4& f4, float& f1,
                                          float4& r4, float& r1) {
    if (t < 368) {
        const int grp = (t >= 184);
        const int i   = 4 * (t - 184 * grp);
        const int vf  = g + 180 * grp;
        const float* __restrict__ fwd = sino + vf * NDET;
        const float* __restrict__ rev = sino + (vf + NPAIR) * NDET;
        f4 = *(const float4*)(fwd + i);
        f1 = fwd[i + 4];
        r4 = *(const float4*)(rev + (732 - i));  // revA[i..i+3] = (w,z,y,x)
        r1 = rev[731 - i];                       // revA[i+4]
    }
}

__device__ __forceinline__ void write_rows(v2h* __restrict__ L,  // [2*NDET]
                                           int t, float4 f4, float f1,
                                           float4 r4, float r1) {
    if (t < 368) {
        const int grp = (t >= 184);
        const int i   = 4 * (t - 184 * grp);
        const float s0 = f4.x + r4.w;
        const float s1 = f4.y + r4.z;
        const float s2 = f4.z + r4.y;
        const float s3 = f4.w + r4.x;
        const float s4 = f1 + r1;
        v2h n0 = __builtin_amdgcn_cvt_pkrtz(s0, s1);
        v2h n1 = __builtin_amdgcn_cvt_pkrtz(s1, s2);
        v2h n2 = __builtin_amdgcn_cvt_pkrtz(s2, s3);
        v2h n3 = __builtin_amdgcn_cvt_pkrtz(s3, s4);
        struct alignas(16) H4 { v2h a, b, c, d; };
        *(H4*)(L + grp * NDET + i) = H4{n0, n1, n2, n3};   // ds_write_b128
    }
}

// One u value: 2-view interp from pairA into accA and pairB into accB.
// 7 VALU + 2 ds_read_b32 serving 4 pixel-view contributions.
__device__ __forceinline__ void visit(const v2h* __restrict__ L,
                                      float u, float& accA, float& accB) {
    const int   i0 = (int)u;                      // u in [3.9, 731.1] always
    const float fr = __builtin_amdgcn_fractf(u);
    const v2h wv = __builtin_amdgcn_cvt_pkrtz(1.0f - fr, fr);
    const v2h PA = L[i0];           // (SA_i0, SA_i0+1)
    const v2h PB = L[NDET + i0];    // same addr reg, offset:2944
    accA = __builtin_amdgcn_fdot2(PA, wv, accA, false);
    accB = __builtin_amdgcn_fdot2(PB, wv, accB, false);
}

// 512 threads = 8 waves; wave = one h row of the top-left quadrant, lanes =
// 64 consecutive w. Thread owns the rotation orbit {(h,w), (511-w,h),
// (511-h,511-w), (w,511-h)}. Grid 1024 = exactly 4 blocks/CU;
// launch_bounds(512,8) -> full 32-wave residency. Bounds check proven
// unnecessary: |g1|,|g2| <= 255.5*sqrt2*1.00621 = 363.6 < 367.5 ->
// u in [3.9, 731.1], i0+1 <= 732 < 736.
__global__ __launch_bounds__(512, 8) void backproject_kernel(
    const float* __restrict__ proj,  // [B, V, D]
    float* __restrict__ out)         // [B, H, W]
{
    __shared__ alignas(16) v2h lds[2][2 * NDET];  // [dbuf][pairA N | pairB N]
    __shared__ v2f cs[NGRP];

    const int tid = threadIdx.x;

    if (tid < NGRP) {
        float s, c;
        sincosf((float)tid * DANG_F, &s, &c);
        cs[tid] = (v2f){c * RATIO_F, s * RATIO_F};
    }

    const int b    = blockIdx.z;
    const int lane = tid & 63;
    const int h    = (int)blockIdx.y * 8 + (tid >> 6);   // [0, 256)
    const int w0   = (int)blockIdx.x * 64 + lane;        // [0, 256)

    const float px = (float)w0 - (float)(IMGW - 1) * 0.5f;
    const float py = (float)(IMGH - 1) * 0.5f - (float)h;

    const float* __restrict__ sino = proj + (size_t)b * NVIEW * NDET;

    // Orbit accumulators: q0=(h,w0), q1=(511-w0,h), q2=(511-h,511-w0),
    // q3=(w0,511-h)   (q_{k+1} = rotate q_k by +90deg).
    float acc0 = 0.f, acc1 = 0.f, acc2 = 0.f, acc3 = 0.f;

    float4 f4 = {0, 0, 0, 0}, r4 = {0, 0, 0, 0};
    float  f1 = 0.f, r1 = 0.f;
    load_rows(sino, 0, tid, f4, f1, r4, r1);
    write_rows(lds[0], tid, f4, f1, r4, r1);
    load_rows(sino, 1, tid, f4, f1, r4, r1);
    __syncthreads();

#pragma unroll 2
    for (int g = 0; g < NGRP; ++g) {
        const int buf = g & 1;
        const v2h* __restrict__ L = lds[buf];
        const v2f t = cs[g];
        // (g1, g2) = px*(c, -s) + py*(s, c)  -- packed fp32
        const v2f m1 = {t.x, -t.y};
        const v2f m2 = {t.y, t.x};
        const v2f pxv = {px, px};
        const v2f pyv = {py, py};
        const v2f gg = __builtin_elementwise_fma(pxv, m1, pyv * m2);
        const v2f cc = {UCENTER, UCENTER};
        const v2f up = cc + gg;   // (C+g1, C+g2)
        const v2f um = cc - gg;   // (C-g1, C-g2)

        visit(L, up.x, acc0, acc1);   // +g1: A->q0, B->q1
        visit(L, um.x, acc2, acc3);   // -g1: A->q2, B->q3
        visit(L, up.y, acc3, acc0);   // +g2: A->q3, B->q0
        visit(L, um.y, acc1, acc2);   // -g2: A->q1, B->q2

        if (g < NGRP - 1) {
            // lds[buf^1] last read at iter g-1, sealed by that iteration's
            // barrier -> safe to overwrite now.
            write_rows(lds[buf ^ 1], tid, f4, f1, r4, r1);
            if (g < NGRP - 2) load_rows(sino, g + 2, tid, f4, f1, r4, r1);
            __syncthreads();
        }
    }

    float* __restrict__ o = out + (size_t)b * IMGH * IMGW;
    const int hm = (IMGH - 1) - h;
    const int wm = (IMGW - 1) - w0;
    o[h  * IMGW + w0] = acc0 * DANG_F;   // q0, coalesced
    o[wm * IMGW + h ] = acc1 * DANG_F;   // q1, scattered (once)
    o[hm * IMGW + wm] = acc2 * DANG_F;   // q2, coalesced
    o[w0 * IMGW + hm] = acc3 * DANG_F;   // q3, scattered (once)
}

extern "C" void kernel_launch(void* const* d_in, const int* in_sizes, int n_in,
                              void* d_out, int out_size, void* d_ws, size_t ws_size,
                              hipStream_t stream) {
    const float* proj = (const float*)d_in[0];
    float* out = (float*)d_out;

    dim3 block(512, 1, 1);
    dim3 grid(4, 32, BATCH);   // 1024 blocks = exactly 4/CU, fully resident
    backproject_kernel<<<grid, block, 0, stream>>>(proj, out);
}